// Round 1
// baseline (2013.394 us; speedup 1.0000x reference)
//
#include <hip/hip_runtime.h>

#define BDIM 4
#define LDIM 4096
#define DDIM 1024
#define KTAPS 128
#define LCHUNK 512

// ---------------------------------------------------------------------------
// GEMM (NT): C[m,n] = sum_k A[m,k] * B[n,k]
// A row-major [M,lda], B row-major [N,ldb], C row-major [M,ldc]
// Tile 128x128, BK=16, 256 threads, 8x8 outputs/thread.
// ---------------------------------------------------------------------------
template <int BM, int BN, int BK>
__global__ __launch_bounds__(256) void gemm_nt(const float* __restrict__ A, int lda,
                                               const float* __restrict__ B, int ldb,
                                               float* __restrict__ C, int ldc, int K) {
    __shared__ float As[BK][BM + 4];
    __shared__ float Bs[BK][BN + 4];

    const int tid = threadIdx.x;
    const int m0 = blockIdx.y * BM;
    const int n0 = blockIdx.x * BN;

    // staging: each thread loads 2 float4 from A and 2 from B per k-tile
    const int srow = tid >> 2;         // 0..63
    const int skq = (tid & 3) << 2;    // 0,4,8,12

    const int tx = tid & 15;           // output col group
    const int ty = tid >> 4;           // output row group

    float acc[8][8];
#pragma unroll
    for (int i = 0; i < 8; ++i)
#pragma unroll
        for (int j = 0; j < 8; ++j) acc[i][j] = 0.f;

    for (int k0 = 0; k0 < K; k0 += BK) {
        const float4 a0 = *(const float4*)&A[(size_t)(m0 + srow) * lda + k0 + skq];
        const float4 a1 = *(const float4*)&A[(size_t)(m0 + srow + 64) * lda + k0 + skq];
        const float4 b0 = *(const float4*)&B[(size_t)(n0 + srow) * ldb + k0 + skq];
        const float4 b1 = *(const float4*)&B[(size_t)(n0 + srow + 64) * ldb + k0 + skq];

        __syncthreads();  // protect previous iteration's LDS reads

        As[skq + 0][srow] = a0.x;
        As[skq + 1][srow] = a0.y;
        As[skq + 2][srow] = a0.z;
        As[skq + 3][srow] = a0.w;
        As[skq + 0][srow + 64] = a1.x;
        As[skq + 1][srow + 64] = a1.y;
        As[skq + 2][srow + 64] = a1.z;
        As[skq + 3][srow + 64] = a1.w;
        Bs[skq + 0][srow] = b0.x;
        Bs[skq + 1][srow] = b0.y;
        Bs[skq + 2][srow] = b0.z;
        Bs[skq + 3][srow] = b0.w;
        Bs[skq + 0][srow + 64] = b1.x;
        Bs[skq + 1][srow + 64] = b1.y;
        Bs[skq + 2][srow + 64] = b1.z;
        Bs[skq + 3][srow + 64] = b1.w;

        __syncthreads();

#pragma unroll
        for (int kk = 0; kk < BK; ++kk) {
            float av[8], bv[8];
            *(float4*)&av[0] = *(const float4*)&As[kk][ty * 4];
            *(float4*)&av[4] = *(const float4*)&As[kk][64 + ty * 4];
            *(float4*)&bv[0] = *(const float4*)&Bs[kk][tx * 4];
            *(float4*)&bv[4] = *(const float4*)&Bs[kk][64 + tx * 4];
#pragma unroll
            for (int i = 0; i < 8; ++i)
#pragma unroll
                for (int j = 0; j < 8; ++j) acc[i][j] += av[i] * bv[j];
        }
    }

#pragma unroll
    for (int i = 0; i < 8; ++i) {
        const int row = m0 + ((i < 4) ? (ty * 4 + i) : (64 + ty * 4 + (i - 4)));
        float4 c0 = make_float4(acc[i][0], acc[i][1], acc[i][2], acc[i][3]);
        float4 c1 = make_float4(acc[i][4], acc[i][5], acc[i][6], acc[i][7]);
        *(float4*)&C[(size_t)row * ldc + n0 + tx * 4] = c0;
        *(float4*)&C[(size_t)row * ldc + n0 + 64 + tx * 4] = c1;
    }
}

// ---------------------------------------------------------------------------
// Causal decay conv + q-gating, in place on the q columns of qkv.
// decay[t] = exp(-10t/127) is geometric => exact IIR with 128-tap truncation:
//   res[l] = r*res[l-1] + src[l] - decay128*src[l-128],  src = k*v
// Each block: one b, 256 d-channels, LCHUNK l's; seeds with direct 128-tap sum.
// ---------------------------------------------------------------------------
__global__ __launch_bounds__(256) void conv_gate(float* __restrict__ qkv,
                                                 const float* __restrict__ decay) {
    __shared__ float sdec[KTAPS];
    if (threadIdx.x < KTAPS) sdec[threadIdx.x] = decay[threadIdx.x];
    __syncthreads();

    const int d = blockIdx.y * 256 + threadIdx.x;
    const int b = blockIdx.z;
    const int l0 = blockIdx.x * LCHUNK;

    const float r = sdec[1];
    const float dlast = r * sdec[KTAPS - 1];  // == decay[128]
    const size_t rs = 3 * DDIM;

    float* base = qkv + (size_t)b * LDIM * rs;
    float* qc = base + d;
    const float* kc = base + DDIM + d;
    const float* vc = base + 2 * DDIM + d;

    float res = 0.f;
    int lstart;
    if (l0 == 0) {
        lstart = 0;
    } else {
        // seed: res[l0] = sum_{t=0}^{127} decay[t] * src[l0 - t]
#pragma unroll 4
        for (int t = 0; t < KTAPS; ++t) {
            const size_t off = (size_t)(l0 - t) * rs;
            res += sdec[t] * kc[off] * vc[off];
        }
        qc[(size_t)l0 * rs] *= res;
        lstart = l0 + 1;
    }

    for (int l = lstart; l < l0 + LCHUNK; ++l) {
        const size_t off = (size_t)l * rs;
        const float s = kc[off] * vc[off];
        if (l == 0) {
            res = sdec[0] * s;
        } else {
            float sub = 0.f;
            if (l >= KTAPS) {
                const size_t o2 = (size_t)(l - KTAPS) * rs;
                sub = dlast * kc[o2] * vc[o2];
            }
            res = r * res + s - sub;
        }
        qc[off] *= res;  // gated = q * res, in place
    }
}

// ---------------------------------------------------------------------------
extern "C" void kernel_launch(void* const* d_in, const int* in_sizes, int n_in,
                              void* d_out, int out_size, void* d_ws, size_t ws_size,
                              hipStream_t stream) {
    const float* x = (const float*)d_in[0];      // [B,L,D]
    const float* Wqkv = (const float*)d_in[1];   // [3D,D]
    const float* Wout = (const float*)d_in[2];   // [D,D]
    const float* decay = (const float*)d_in[3];  // [128]
    float* out = (float*)d_out;                  // [B,L,D]

    float* qkv = (float*)d_ws;  // [B*L, 3D] fp32 = 192 MB

    const int M = BDIM * LDIM;  // 16384

    // GEMM1: qkv = x @ Wqkv^T   [M,1024] x [3072,1024]^T
    dim3 g1(3 * DDIM / 128, M / 128);
    gemm_nt<128, 128, 16><<<g1, 256, 0, stream>>>(x, DDIM, Wqkv, DDIM, qkv, 3 * DDIM, DDIM);

    // conv + gate (in-place on q columns of qkv)
    dim3 g2(LDIM / LCHUNK, DDIM / 256, BDIM);
    conv_gate<<<g2, 256, 0, stream>>>(qkv, decay);

    // GEMM2: out = gated @ Wout^T   [M,1024](lda=3072) x [1024,1024]^T
    dim3 g3(DDIM / 128, M / 128);
    gemm_nt<128, 128, 16><<<g3, 256, 0, stream>>>(qkv, 3 * DDIM, Wout, DDIM, out, DDIM, DDIM);
}